// Round 10
// baseline (3584.967 us; speedup 1.0000x reference)
//
#include <hip/hip_runtime.h>
#include <stdint.h>

typedef unsigned short u16;
typedef __attribute__((ext_vector_type(8))) short bf16x8;
typedef __attribute__((ext_vector_type(4))) float fx4;
typedef __attribute__((ext_vector_type(2))) unsigned int u32x2;
typedef __attribute__((ext_vector_type(4))) unsigned int u32x4;

#define MFMA16(a, b, c) __builtin_amdgcn_mfma_f32_16x16x32_bf16((a), (b), (c), 0, 0, 0)

// ---- workspace layout (bytes) — round-7 footprint ----
// Ring shrunk 8->4 slots (4 x 64KB per group = 256KB); the freed space holds
// TEX: the TAGGED h-exchange buffer. TEX dword = {hi16 = step-tag, lo16 = bf16 h}.
// One dword store publishes value+tag atomically -> no store-drain, no flag,
// no flag-poll: reader polls the data itself (all sc0sc1 = proven L3 path).
// 2 rotating TEX slots are safe: a writer overwrites h(T-2) only after it has
// consumed all peers' h(T-1), which implies every peer consumed h(T-2).
#define OFF_X      0u            // x bf16 [B][L][256]             67108864
#define OFF_H      67108864u     // H bf16 [577][256][256]         75628544
#define RING_OFF   134348800u    // z-ring [16 g][4 slot][4 j][256 u][16 r] fp32 = 4MB
#define OFF_TEX    138543104u    // tagged h [2 slot][16 g][16 row][256 u] dword = 524288
#define OFF_ENCWT  142737408u    // enc_W^T bf16 [1024][256]         524288
#define OFF_ENCUT  143261696u    // enc_U^T bf16 [1024][256]         524288
#define OFF_CELLT  143785984u    // (cell_W+cell_U)^T bf16           524288
#define OFF_CONVKT 144310272u    // conv k^T bf16 [256][320]         163840
#define OFF_BWT    144474112u    // back_W^T bf16 [64][256]           32768
#define OFF_FWT    144506880u    // fore_W^T bf16 [32][256]           16384
#define OFF_BAR    144523264u    // per group: hbar @g*64, pcnt_z @g*64+32
// end: 144524288 (same as round 7). H[513..576] (= ring+TEX area) is reused by
// dec_kernel AFTER enc_fused (stream-ordered) exactly as in round 7.

#define POLL_BUDGET (1 << 25)

__device__ __forceinline__ u16 f2bf(float f) {
    uint32_t u = __builtin_bit_cast(uint32_t, f);
    u += 0x7FFFu + ((u >> 16) & 1u);   // RNE
    return (u16)(u >> 16);
}
__device__ __forceinline__ float sigm(float x) { return 1.0f / (1.0f + __expf(-x)); }
__device__ __forceinline__ float tanh_f(float x) { return 1.0f - 2.0f / (__expf(2.0f * x) + 1.0f); }
__device__ __forceinline__ void vmcnt0() { asm volatile("s_waitcnt vmcnt(0)" ::: "memory"); }

// ---------------------------------------------------------------------------
__global__ void zero_kernel(unsigned char* ws) {
    int i = blockIdx.x * blockDim.x + threadIdx.x;   // 16384 threads
    uint32_t* h0 = (uint32_t*)(ws + OFF_H);          // H slot 0 (kept, harmless)
    for (int k = i; k < 32768; k += 16384) h0[k] = 0u;
    uint32_t* tex = (uint32_t*)(ws + OFF_TEX);
    for (int k = i; k < 65536; k += 16384) {
        tex[k] = 0x00010000u;        // slot 0: tag=1, h=bf16(0) -> h(0) ready
        tex[65536 + k] = 0u;         // slot 1: invalid tag
    }
    if (i < 256) ((uint32_t*)(ws + OFF_BAR))[i] = 0u;   // hbar + pcnt_z
}

// ---------------------------------------------------------------------------
__global__ void prep_kernel(const float* enc_W, const float* enc_U, const float* cell_W,
                            const float* cell_U, const float* conv_k, const float* back_W,
                            const float* fore_W, unsigned char* ws) {
    u16* encWt = (u16*)(ws + OFF_ENCWT);
    u16* encUt = (u16*)(ws + OFF_ENCUT);
    u16* cellT = (u16*)(ws + OFF_CELLT);
    u16* convKt = (u16*)(ws + OFF_CONVKT);
    u16* bwt = (u16*)(ws + OFF_BWT);
    u16* fwt = (u16*)(ws + OFF_FWT);
    int idx = blockIdx.x * blockDim.x + threadIdx.x;
    int stride = gridDim.x * blockDim.x;
    for (int i = idx; i < 262144; i += stride) {
        int n = i >> 8, k = i & 255;
        encWt[i] = f2bf(enc_W[k * 1024 + n]);
        encUt[i] = f2bf(enc_U[k * 1024 + n]);
        cellT[i] = f2bf(cell_W[k * 1024 + n] + cell_U[k * 1024 + n]);
    }
    for (int i = idx; i < 81920; i += stride) {
        int u = i / 320, rem = i - u * 320;
        convKt[i] = f2bf(conv_k[rem * 256 + u]);
    }
    for (int i = idx; i < 16384; i += stride) {
        int n = i >> 8, k = i & 255;
        bwt[i] = f2bf(back_W[k * 64 + n]);
    }
    for (int i = idx; i < 8192; i += stride) {
        int n = i >> 8, k = i & 255;
        fwt[i] = f2bf(fore_W[k * 32 + n]);
    }
}

// ---------------------------------------------------------------------------
// Conv1D(same,k=5)+bias+ReLU as MFMA GEMM (verbatim passing code)
__global__ __launch_bounds__(256) void conv_kernel(const float* __restrict__ in,
                                                   const float* __restrict__ conv_b,
                                                   unsigned char* ws) {
    const u16* kt = (const u16*)(ws + OFF_CONVKT);
    u16* xout = (u16*)(ws + OFF_X);
    int w = threadIdx.x >> 6, lane = threadIdx.x & 63;
    int m = lane & 15, q = lane >> 4;
    int mt = blockIdx.x * 4 + w;
    int r0 = mt * 16;
    int b = r0 >> 9;
    int l0 = r0 & 511;

    fx4 acc[16];
#pragma unroll
    for (int nt = 0; nt < 16; ++nt) acc[nt] = (fx4){0.f, 0.f, 0.f, 0.f};

#pragma unroll
    for (int s = 0; s < 10; ++s) {
        int k0 = s * 32 + q * 8;
        int kk = k0 >> 6, c = k0 & 63;
        int l2 = l0 + m + kk - 2;
        bf16x8 af = {0, 0, 0, 0, 0, 0, 0, 0};
        if (l2 >= 0 && l2 < 512) {
            const float* src = in + (((b << 9) + l2) << 6) + c;
            fx4 f0 = *(const fx4*)src;
            fx4 f1 = *(const fx4*)(src + 4);
            af[0] = (short)f2bf(f0[0]); af[1] = (short)f2bf(f0[1]);
            af[2] = (short)f2bf(f0[2]); af[3] = (short)f2bf(f0[3]);
            af[4] = (short)f2bf(f1[0]); af[5] = (short)f2bf(f1[1]);
            af[6] = (short)f2bf(f1[2]); af[7] = (short)f2bf(f1[3]);
        }
#pragma unroll
        for (int nt = 0; nt < 16; ++nt) {
            bf16x8 bf = *(const bf16x8*)(kt + (nt * 16 + m) * 320 + k0);
            acc[nt] = MFMA16(af, bf, acc[nt]);
        }
    }
#pragma unroll
    for (int nt = 0; nt < 16; ++nt) {
        int u = nt * 16 + m;
        float bias = conv_b[u];
#pragma unroll
        for (int r = 0; r < 4; ++r) {
            float v = acc[nt][r] + bias;
            v = v > 0.f ? v : 0.f;
            int row = r0 + q * 4 + r;
            xout[row * 256 + u] = f2bf(v);
        }
    }
}

// ---------------------------------------------------------------------------
// Encoder: 128 blocks x 256 threads (proven launch shape), STATIC groups.
// Blocks 0..63  : consumers (g=bid&15, p=bid>>4). h-exchange via TEX tagged
//   dwords: publish fire-and-forget, read poll-until-tag-fresh. No vmcnt or
//   flag on the critical path (outstanding stores drain under the NEXT step's
//   retry vmcnt0). hbar++ per step retains its role: producer backpressure +
//   decoder start gate (final step does vmcnt0 first so H[512] is certified).
// Blocks 64..127: producers — round-7 verbatim except ring depth 4 (t&3) and
//   the matching backpressure constant.
__global__ __launch_bounds__(256, 1) void enc_fused(const float* __restrict__ enc_b,
                                                    unsigned char* ws) {
    __shared__ u16 hbuf[1024];        // [16 rows][64 units] bf16 (H backcast)
    __shared__ uint32_t hbufd[1024];  // [16 rows][64 units] tagged dwords (TEX)
    int tid = threadIdx.x;
    int w = tid >> 6, lane = tid & 63, m = lane & 15, q = lane >> 4;
    int bid = blockIdx.x;
    u16* H = (u16*)(ws + OFF_H);
    int budget = POLL_BUDGET;

    if (bid >= 64) {
        // ================= producer =================
        int idx = bid - 64, g = idx & 15, p = idx >> 4;
        int b0 = g * 16;
        int un0 = p * 64 + w * 16;
        const u16* encWt = (const u16*)(ws + OFF_ENCWT);
        const u16* xbf = (const u16*)(ws + OFF_X);
        float* ringg = (float*)(ws + RING_OFF + (size_t)g * 262144u);
        int* hbar = (int*)(ws + OFF_BAR + g * 64);
        int* pz = (int*)(ws + OFF_BAR + g * 64 + 32);

        bf16x8 wfr[4][8];
        float bi[4];
#pragma unroll
        for (int j = 0; j < 4; ++j) {
            int row = j * 256 + un0 + m;
            bi[j] = enc_b[row];
#pragma unroll
            for (int ks = 0; ks < 8; ++ks)
                wfr[j][ks] = *(const bf16x8*)(encWt + row * 256 + ks * 32 + q * 8);
        }
        const u16* xrow = xbf + (size_t)(b0 + m) * (512 * 256) + q * 8;
        bf16x8 xa[8];
#pragma unroll
        for (int s = 0; s < 8; ++s) xa[s] = *(const bf16x8*)(xrow + s * 32);

        for (int t = 0; t < 512; ++t) {
            fx4 a0 = (fx4){bi[0], bi[0], bi[0], bi[0]};
            fx4 a1 = (fx4){bi[1], bi[1], bi[1], bi[1]};
            fx4 a2 = (fx4){bi[2], bi[2], bi[2], bi[2]};
            fx4 a3 = (fx4){bi[3], bi[3], bi[3], bi[3]};
#pragma unroll
            for (int ks = 0; ks < 8; ++ks) {
                a0 = MFMA16(xa[ks], wfr[0][ks], a0);
                a1 = MFMA16(xa[ks], wfr[1][ks], a1);
                a2 = MFMA16(xa[ks], wfr[2][ks], a2);
                a3 = MFMA16(xa[ks], wfr[3][ks], a3);
            }
            // slot layout: [j][u][16 r] fp32; lane (m,q) stores rows q*4..+3
            float* zs = ringg + (t & 3) * 16384 + (un0 + m) * 16 + q * 4;
            asm volatile("global_store_dwordx4 %0, %1, off sc0 sc1" :: "v"(zs), "v"(a0) : "memory");
            asm volatile("global_store_dwordx4 %0, %1, off sc0 sc1" :: "v"(zs + 4096), "v"(a1) : "memory");
            asm volatile("global_store_dwordx4 %0, %1, off sc0 sc1" :: "v"(zs + 8192), "v"(a2) : "memory");
            asm volatile("global_store_dwordx4 %0, %1, off sc0 sc1" :: "v"(zs + 12288), "v"(a3) : "memory");
            if (t < 511) {
                const u16* xA = xrow + (size_t)(t + 1) * 256;   // prefetch next x
#pragma unroll
                for (int s = 0; s < 8; ++s) xa[s] = *(const bf16x8*)(xA + s * 32);
                if (tid == 0 && t >= 3) {
                    // next step overwrites slot (t+1)&3 (holds z[t-3]); all 4
                    // consumer WGs must have finished reading step t-3:
                    int tgt = 4 * (t - 2);
                    while (__hip_atomic_load(hbar, __ATOMIC_RELAXED, __HIP_MEMORY_SCOPE_AGENT) < tgt
                           && --budget > 0) {}
                }
            }
            vmcnt0();                 // z stores (and prefetch) complete
            __syncthreads();
            if (tid == 0)
                __hip_atomic_fetch_add(pz, 1, __ATOMIC_RELAXED, __HIP_MEMORY_SCOPE_AGENT);
        }
        return;
    }

    // ================= consumer =================
    int g = bid & 15, p = bid >> 4;
    int b0 = g * 16;
    int un0 = p * 64 + w * 16;
    const u16* encUt = (const u16*)(ws + OFF_ENCUT);
    const float* ringg = (const float*)(ws + RING_OFF + (size_t)g * 262144u);
    float* csaveg = (float*)(ws + OFF_X + (size_t)g * 4194304u);
    int* hbar = (int*)(ws + OFF_BAR + g * 64);
    int* pz = (int*)(ws + OFF_BAR + g * 64 + 32);

    bf16x8 ufrag[4][8];
#pragma unroll
    for (int gi = 0; gi < 4; ++gi) {
#pragma unroll
        for (int s = 0; s < 8; ++s)
            ufrag[gi][s] = *(const bf16x8*)(encUt + (gi * 256 + un0 + m) * 256 + s * 32 + q * 8);
    }
    float creg[4] = {0.f, 0.f, 0.f, 0.f};
    int zk = 0;   // cached producer progress (lane 0)

    for (int t = 0; t < 512; ++t) {
        // ---- z[t] certified? (cached; usually skipped — producers run ahead)
        if (lane == 0 && zk <= t) {
            while (--budget > 0) {
                int v = __hip_atomic_load(pz, __ATOMIC_RELAXED, __HIP_MEMORY_SCOPE_AGENT);
                if (v >= 4 * (t + 1)) { zk = v >> 2; break; }
            }
        }
        asm volatile("" ::: "memory");

        // ---- issue z loads early (latency overlaps the TEX poll) ----
        const float* zb = ringg + (t & 3) * 16384 + (un0 + m) * 16 + q * 4;
        fx4 z0, z1, z2, z3;
        asm volatile("global_load_dwordx4 %0, %1, off sc0 sc1" : "=v"(z0) : "v"(zb));
        asm volatile("global_load_dwordx4 %0, %1, off sc0 sc1" : "=v"(z1) : "v"(zb + 4096));
        asm volatile("global_load_dwordx4 %0, %1, off sc0 sc1" : "=v"(z2) : "v"(zb + 8192));
        asm volatile("global_load_dwordx4 %0, %1, off sc0 sc1" : "=v"(z3) : "v"(zb + 12288));

        // ---- TEX poll: h(t) tagged dwords, tag must equal t+1 ----
        // lane (m,q) reads row m, units {s*32 + q*8 .. +8} for s=0..7.
        const uint32_t* texr = (const uint32_t*)(ws + OFF_TEX + (uint32_t)(t & 1) * 262144u
                                                 + (uint32_t)g * 16384u) + m * 256 + q * 8;
        uint32_t expect = (uint32_t)(t + 1);
        u32x4 ld0[8], ld1[8];
        for (;;) {
#pragma unroll
            for (int s = 0; s < 8; ++s) {
                asm volatile("global_load_dwordx4 %0, %1, off sc0 sc1"
                             : "=v"(ld0[s]) : "v"(texr + s * 32));
                asm volatile("global_load_dwordx4 %0, %1, off sc0 sc1"
                             : "=v"(ld1[s]) : "v"(texr + s * 32 + 4));
            }
            vmcnt0();   // also drains our previous step's fire-and-forget stores
            int fresh = 1;
#pragma unroll
            for (int s = 0; s < 8; ++s) {
                fresh &= (ld0[s][0] >> 16) == expect; fresh &= (ld0[s][1] >> 16) == expect;
                fresh &= (ld0[s][2] >> 16) == expect; fresh &= (ld0[s][3] >> 16) == expect;
                fresh &= (ld1[s][0] >> 16) == expect; fresh &= (ld1[s][1] >> 16) == expect;
                fresh &= (ld1[s][2] >> 16) == expect; fresh &= (ld1[s][3] >> 16) == expect;
            }
            if (__all(fresh)) break;
            if (--budget < 0) break;   // watchdog: free-run instead of hang
        }
        asm volatile("" ::: "memory");

        // ---- unpack lo16s -> bf16x8 fragments ----
        bf16x8 ha[8];
#pragma unroll
        for (int s = 0; s < 8; ++s) {
            u32x4 pk;
            pk[0] = (ld0[s][0] & 0xFFFFu) | (ld0[s][1] << 16);
            pk[1] = (ld0[s][2] & 0xFFFFu) | (ld0[s][3] << 16);
            pk[2] = (ld1[s][0] & 0xFFFFu) | (ld1[s][1] << 16);
            pk[3] = (ld1[s][2] & 0xFFFFu) | (ld1[s][3] << 16);
            ha[s] = __builtin_bit_cast(bf16x8, pk);
        }

        fx4 acc[4];
#pragma unroll
        for (int gi = 0; gi < 4; ++gi) acc[gi] = (fx4){0.f, 0.f, 0.f, 0.f};
#pragma unroll
        for (int s = 0; s < 8; ++s) {
#pragma unroll
            for (int gi = 0; gi < 4; ++gi)
                acc[gi] = MFMA16(ha[s], ufrag[gi][s], acc[gi]);
        }

        float hreg[4];
#pragma unroll
        for (int r = 0; r < 4; ++r) {
            float pi = acc[0][r] + z0[r];
            float pf = acc[1][r] + z1[r];
            float pg = acc[2][r] + z2[r];
            float po = acc[3][r] + z3[r];
            float cv = sigm(pf) * creg[r] + sigm(pi) * tanh_f(pg);
            creg[r] = cv;
            hreg[r] = sigm(po) * tanh_f(cv);
        }
        // ---- stage h(t+1) into LDS (bf16 for H, tagged dword for TEX) ----
        __syncthreads();   // guard LDS buffers against previous iteration's flush
        uint32_t tagw = (uint32_t)(t + 2) << 16;
#pragma unroll
        for (int r = 0; r < 4; ++r) {
            int ul = w * 16 + m;
            u16 hb = f2bf(hreg[r]);
            hbuf[(q * 4 + r) * 64 + ul] = hb;
            hbufd[(q * 4 + r) * 64 + ul] = tagw | (uint32_t)hb;
        }
        __syncthreads();
        {   // coalesced fire-and-forget flush: H (backcast) + TEX (exchange)
            int row = tid >> 4, c4 = (tid & 15) * 4;
            u32x2 hv = *(const u32x2*)&hbuf[row * 64 + c4];
            const u16* hw = H + (size_t)(t + 1) * 65536 + (b0 + row) * 256 + p * 64 + c4;
            asm volatile("global_store_dwordx2 %0, %1, off sc0 sc1" :: "v"(hw), "v"(hv) : "memory");
            u32x4 tv = *(const u32x4*)&hbufd[row * 64 + c4];
            uint32_t* texw = (uint32_t*)(ws + OFF_TEX + (uint32_t)((t + 1) & 1) * 262144u
                                         + (uint32_t)g * 16384u) + row * 256 + p * 64 + c4;
            asm volatile("global_store_dwordx4 %0, %1, off sc0 sc1" :: "v"(texw), "v"(tv) : "memory");
        }
        if (t == 511) vmcnt0();   // certify H[512] (+all H) before the final signal
        if (tid == 0)
            __hip_atomic_fetch_add(hbar, 1, __ATOMIC_RELAXED, __HIP_MEMORY_SCOPE_AGENT);
    }

    // hand off c to the decoder (normal stores; kernel-end flush makes visible)
#pragma unroll
    for (int r = 0; r < 4; ++r)
        csaveg[(q * 4 + r) * 256 + un0 + m] = creg[r];
}

// ---------------------------------------------------------------------------
// Decoder: verbatim round-7 passing code (runs after enc_fused; overwrites the
// then-dead ring/TEX region at H[513..576]).
__global__ __launch_bounds__(256, 1) void dec_kernel(const float* __restrict__ cell_b,
                                                     unsigned char* ws) {
    int tid = threadIdx.x;
    int w = tid >> 6, lane = tid & 63, m = lane & 15, q = lane >> 4;
    int bid = blockIdx.x;
    int g = bid & 15, p = bid >> 4;
    int b0 = g * 16;
    int un0 = p * 64 + w * 16;
    int budget = POLL_BUDGET;

    const u16* cellT = (const u16*)(ws + OFF_CELLT);
    u16* H = (u16*)(ws + OFF_H);
    const float* csaveg = (const float*)(ws + OFF_X + (size_t)g * 4194304u);
    int* bar = (int*)(ws + OFF_BAR + g * 64);

    bf16x8 wfrag[4][8];
#pragma unroll
    for (int gi = 0; gi < 4; ++gi) {
#pragma unroll
        for (int s = 0; s < 8; ++s)
            wfrag[gi][s] = *(const bf16x8*)(cellT + (gi * 256 + un0 + m) * 256 + s * 32 + q * 8);
    }
    float bi[4], creg[4];
#pragma unroll
    for (int gi = 0; gi < 4; ++gi) bi[gi] = cell_b[gi * 256 + un0 + m];
#pragma unroll
    for (int r = 0; r < 4; ++r) creg[r] = csaveg[(q * 4 + r) * 256 + un0 + m];

    for (int t = 0; t < 64; ++t) {
        if (lane == 0) {
            int tgt = 2048 + 4 * t;   // encoder left hbar at 4*512 = 2048
            while (__hip_atomic_load(bar, __ATOMIC_RELAXED, __HIP_MEMORY_SCOPE_AGENT) < tgt
                   && --budget > 0) {}
        }
        asm volatile("" ::: "memory");

        const u16* hA = H + (size_t)(512 + t) * 65536 + (b0 + m) * 256 + q * 8;
        bf16x8 ha[8];
#pragma unroll
        for (int s = 0; s < 8; ++s) ha[s] = *(const bf16x8*)(hA + s * 32);
        fx4 acc[4];
#pragma unroll
        for (int gi = 0; gi < 4; ++gi) acc[gi] = (fx4){bi[gi], bi[gi], bi[gi], bi[gi]};
#pragma unroll
        for (int s = 0; s < 8; ++s) {
#pragma unroll
            for (int gi = 0; gi < 4; ++gi)
                acc[gi] = MFMA16(ha[s], wfrag[gi][s], acc[gi]);
        }

        const u16* hw = H + (size_t)(513 + t) * 65536 + un0 + m;
#pragma unroll
        for (int r = 0; r < 4; ++r) {
            float cv = sigm(acc[1][r]) * creg[r] + sigm(acc[0][r]) * tanh_f(acc[2][r]);
            creg[r] = cv;
            float hv = sigm(acc[3][r]) * tanh_f(cv);
            uint32_t hb = (uint32_t)f2bf(hv);
            const u16* hp = hw + (b0 + q * 4 + r) * 256;
            asm volatile("global_store_short %0, %1, off sc0 sc1" :: "v"(hp), "v"(hb) : "memory");
        }
        vmcnt0();
        __syncthreads();
        if (tid == 0)
            __hip_atomic_fetch_add(bar, 1, __ATOMIC_RELAXED, __HIP_MEMORY_SCOPE_AGENT);
    }
}

// ---------------------------------------------------------------------------
// out[(b*seqlen+s)*ncols+col] = H-slot A[s][b][:] @ Bt[col][:] + bias[col]
__global__ __launch_bounds__(256) void out_gemm(const u16* __restrict__ A,
                                                const u16* __restrict__ Bt,
                                                const float* __restrict__ bias,
                                                float* __restrict__ out,
                                                int ncols, int seqlen) {
    int w = threadIdx.x >> 6, lane = threadIdx.x & 63, m = lane & 15, q = lane >> 4;
    int mt = blockIdx.x * 4 + w;
    int s = mt >> 4;
    int b0 = (mt & 15) * 16;
    bf16x8 af[8];
    const u16* Arow = A + ((size_t)s * 256 + b0 + m) * 256 + q * 8;
#pragma unroll
    for (int ss = 0; ss < 8; ++ss) af[ss] = *(const bf16x8*)(Arow + ss * 32);
    int ntiles = ncols >> 4;
    for (int nt = 0; nt < ntiles; ++nt) {
        fx4 acc = (fx4){0.f, 0.f, 0.f, 0.f};
#pragma unroll
        for (int ss = 0; ss < 8; ++ss) {
            bf16x8 bf = *(const bf16x8*)(Bt + (nt * 16 + m) * 256 + ss * 32 + q * 8);
            acc = MFMA16(af[ss], bf, acc);
        }
        int col = nt * 16 + m;
        float bv = bias[col];
#pragma unroll
        for (int r = 0; r < 4; ++r) {
            int b = b0 + q * 4 + r;
            out[((size_t)b * seqlen + s) * ncols + col] = acc[r] + bv;
        }
    }
}

// ---------------------------------------------------------------------------
extern "C" void kernel_launch(void* const* d_in, const int* in_sizes, int n_in,
                              void* d_out, int out_size, void* d_ws, size_t ws_size,
                              hipStream_t stream) {
    const float* inputs = (const float*)d_in[0];
    const float* conv_k = (const float*)d_in[1];
    const float* conv_b = (const float*)d_in[2];
    const float* enc_W  = (const float*)d_in[3];
    const float* enc_U  = (const float*)d_in[4];
    const float* enc_b  = (const float*)d_in[5];
    const float* cell_W = (const float*)d_in[6];
    const float* cell_U = (const float*)d_in[7];
    const float* cell_b = (const float*)d_in[8];
    const float* fore_W = (const float*)d_in[9];
    const float* fore_b = (const float*)d_in[10];
    const float* back_W = (const float*)d_in[11];
    const float* back_b = (const float*)d_in[12];
    unsigned char* ws = (unsigned char*)d_ws;
    float* out = (float*)d_out;

    zero_kernel<<<64, 256, 0, stream>>>(ws);
    prep_kernel<<<1024, 256, 0, stream>>>(enc_W, enc_U, cell_W, cell_U, conv_k, back_W, fore_W, ws);
    conv_kernel<<<2048, 256, 0, stream>>>(inputs, conv_b, ws);
    enc_fused<<<128, 256, 0, stream>>>(enc_b, ws);
    dec_kernel<<<64, 256, 0, stream>>>(cell_b, ws);

    const u16* H = (const u16*)(ws + OFF_H);
    // backcast: slots 1..512 -> out[b][l][64] at float offset 524288
    out_gemm<<<2048, 256, 0, stream>>>(H + (size_t)1 * 65536, (const u16*)(ws + OFF_BWT),
                                       back_b, out + 524288, 64, 512);
    // forecast: slots 513..576 -> out[b][j][32]
    out_gemm<<<256, 256, 0, stream>>>(H + (size_t)513 * 65536, (const u16*)(ws + OFF_FWT),
                                      fore_b, out, 32, 64);
}

// Round 11
// 2323.293 us; speedup vs baseline: 1.5431x; 1.5431x over previous
//
#include <hip/hip_runtime.h>
#include <stdint.h>

typedef unsigned short u16;
typedef __attribute__((ext_vector_type(8))) short bf16x8;
typedef __attribute__((ext_vector_type(4))) float fx4;
typedef __attribute__((ext_vector_type(2))) unsigned int u32x2;
typedef __attribute__((ext_vector_type(4))) unsigned int u32x4;

#define MFMA16(a, b, c) __builtin_amdgcn_mfma_f32_16x16x32_bf16((a), (b), (c), 0, 0, 0)

// ---- workspace layout (bytes) — round-7 PASSING layout ----
#define OFF_X      0u            // x bf16 [B][L][256]             67108864
#define OFF_H      67108864u     // H bf16 [577][256][256]         75628544
#define RING_OFF   134348800u    // z-ring [16 g][8 slot][4 j][256 u][16 r] fp32
#define OFF_ENCWT  142737408u    // enc_W^T bf16 [1024][256]         524288
#define OFF_ENCUT  143261696u    // enc_U^T bf16 [1024][256]         524288
#define OFF_CELLT  143785984u    // (cell_W+cell_U)^T bf16           524288
#define OFF_CONVKT 144310272u    // conv k^T bf16 (dead after conv -> packed flags)
#define OFF_BWT    144474112u    // back_W^T bf16 [64][256]           32768
#define OFF_FWT    144506880u    // fore_W^T bf16 [32][256]           16384
#define OFF_BAR    144523264u    // per group: pcnt_z @g*64+32 (hbar slot unused now)
// Packed step-flags (carved from dead convKt region): [16 g][8 slot][4 p] dwords
// = 2048 B. One dwordx4 read returns ALL FOUR group flags for a step-slot —
// the round-7 wait did 3 SEQUENTIAL flag round-trips (~1.2us/step); this is 1.
#define OFF_FLG2   (OFF_CONVKT)

#define POLL_BUDGET (1 << 25)

__device__ __forceinline__ u16 f2bf(float f) {
    uint32_t u = __builtin_bit_cast(uint32_t, f);
    u += 0x7FFFu + ((u >> 16) & 1u);   // RNE
    return (u16)(u >> 16);
}
__device__ __forceinline__ float sigm(float x) { return 1.0f / (1.0f + __expf(-x)); }
__device__ __forceinline__ float tanh_f(float x) { return 1.0f - 2.0f / (__expf(2.0f * x) + 1.0f); }
__device__ __forceinline__ void vmcnt0() { asm volatile("s_waitcnt vmcnt(0)" ::: "memory"); }

// one-shot load of a group's 4 packed flags (L3-coherent path)
__device__ __forceinline__ u32x4 ld_flags4(const void* p) {
    u32x4 v;
    asm volatile("global_load_dwordx4 %0, %1, off sc0 sc1\ns_waitcnt vmcnt(0)"
                 : "=v"(v) : "v"(p) : "memory");
    return v;
}
__device__ __forceinline__ void st_flag(void* p, uint32_t v) {
    asm volatile("global_store_dword %0, %1, off sc0 sc1" :: "v"(p), "v"(v) : "memory");
}

// ---------------------------------------------------------------------------
__global__ void zero_kernel(unsigned char* ws) {
    int i = blockIdx.x * blockDim.x + threadIdx.x;   // 16384 threads
    uint32_t* h0 = (uint32_t*)(ws + OFF_H);          // slot 0 = h(0): 131072 B
    for (int k = i; k < 32768; k += 16384) h0[k] = 0u;
    if (i < 256) ((uint32_t*)(ws + OFF_BAR))[i] = 0u;   // pz counters
}

// init packed flags AFTER conv_kernel (convKt region is then dead)
__global__ void zero2_kernel(unsigned char* ws) {
    uint32_t* p = (uint32_t*)(ws + OFF_FLG2);
    int i = threadIdx.x;
    for (int k = i; k < 512; k += 256) p[k] = 0u;
}

// ---------------------------------------------------------------------------
__global__ void prep_kernel(const float* enc_W, const float* enc_U, const float* cell_W,
                            const float* cell_U, const float* conv_k, const float* back_W,
                            const float* fore_W, unsigned char* ws) {
    u16* encWt = (u16*)(ws + OFF_ENCWT);
    u16* encUt = (u16*)(ws + OFF_ENCUT);
    u16* cellT = (u16*)(ws + OFF_CELLT);
    u16* convKt = (u16*)(ws + OFF_CONVKT);
    u16* bwt = (u16*)(ws + OFF_BWT);
    u16* fwt = (u16*)(ws + OFF_FWT);
    int idx = blockIdx.x * blockDim.x + threadIdx.x;
    int stride = gridDim.x * blockDim.x;
    for (int i = idx; i < 262144; i += stride) {
        int n = i >> 8, k = i & 255;
        encWt[i] = f2bf(enc_W[k * 1024 + n]);
        encUt[i] = f2bf(enc_U[k * 1024 + n]);
        cellT[i] = f2bf(cell_W[k * 1024 + n] + cell_U[k * 1024 + n]);
    }
    for (int i = idx; i < 81920; i += stride) {
        int u = i / 320, rem = i - u * 320;
        convKt[i] = f2bf(conv_k[rem * 256 + u]);
    }
    for (int i = idx; i < 16384; i += stride) {
        int n = i >> 8, k = i & 255;
        bwt[i] = f2bf(back_W[k * 64 + n]);
    }
    for (int i = idx; i < 8192; i += stride) {
        int n = i >> 8, k = i & 255;
        fwt[i] = f2bf(fore_W[k * 32 + n]);
    }
}

// ---------------------------------------------------------------------------
// Conv1D(same,k=5)+bias+ReLU as MFMA GEMM (verbatim passing code)
__global__ __launch_bounds__(256) void conv_kernel(const float* __restrict__ in,
                                                   const float* __restrict__ conv_b,
                                                   unsigned char* ws) {
    const u16* kt = (const u16*)(ws + OFF_CONVKT);
    u16* xout = (u16*)(ws + OFF_X);
    int w = threadIdx.x >> 6, lane = threadIdx.x & 63;
    int m = lane & 15, q = lane >> 4;
    int mt = blockIdx.x * 4 + w;
    int r0 = mt * 16;
    int b = r0 >> 9;
    int l0 = r0 & 511;

    fx4 acc[16];
#pragma unroll
    for (int nt = 0; nt < 16; ++nt) acc[nt] = (fx4){0.f, 0.f, 0.f, 0.f};

#pragma unroll
    for (int s = 0; s < 10; ++s) {
        int k0 = s * 32 + q * 8;
        int kk = k0 >> 6, c = k0 & 63;
        int l2 = l0 + m + kk - 2;
        bf16x8 af = {0, 0, 0, 0, 0, 0, 0, 0};
        if (l2 >= 0 && l2 < 512) {
            const float* src = in + (((b << 9) + l2) << 6) + c;
            fx4 f0 = *(const fx4*)src;
            fx4 f1 = *(const fx4*)(src + 4);
            af[0] = (short)f2bf(f0[0]); af[1] = (short)f2bf(f0[1]);
            af[2] = (short)f2bf(f0[2]); af[3] = (short)f2bf(f0[3]);
            af[4] = (short)f2bf(f1[0]); af[5] = (short)f2bf(f1[1]);
            af[6] = (short)f2bf(f1[2]); af[7] = (short)f2bf(f1[3]);
        }
#pragma unroll
        for (int nt = 0; nt < 16; ++nt) {
            bf16x8 bf = *(const bf16x8*)(kt + (nt * 16 + m) * 320 + k0);
            acc[nt] = MFMA16(af, bf, acc[nt]);
        }
    }
#pragma unroll
    for (int nt = 0; nt < 16; ++nt) {
        int u = nt * 16 + m;
        float bias = conv_b[u];
#pragma unroll
        for (int r = 0; r < 4; ++r) {
            float v = acc[nt][r] + bias;
            v = v > 0.f ? v : 0.f;
            int row = r0 + q * 4 + r;
            xout[row * 256 + u] = f2bf(v);
        }
    }
}

// ---------------------------------------------------------------------------
// Encoder: round-7 structure (PASSING) with ONE change — packed dwordx4 flags.
// Blocks 0..63  : consumers (g=bid&15, p=bid>>4): h-part MFMAs from U-frags in
//   VGPRs; z from the producer ring; h exchange via sc0sc1 H stores certified
//   by a per-(g,slot) packed flag line written after vmcnt0.
// Blocks 64..127: producers: z = x@W + b into the 8-deep ring; backpressure by
//   reading the packed consumer flags; pz counter certifies z slots.
__global__ __launch_bounds__(256, 1) void enc_fused(const float* __restrict__ enc_b,
                                                    unsigned char* ws) {
    __shared__ u16 hbuf[1024];   // [16 rows][64 units] transpose buffer (2KB)
    int tid = threadIdx.x;
    int w = tid >> 6, lane = tid & 63, m = lane & 15, q = lane >> 4;
    int bid = blockIdx.x;
    u16* H = (u16*)(ws + OFF_H);
    int budget = POLL_BUDGET;

    if (bid >= 64) {
        // ================= producer =================
        int idx = bid - 64, g = idx & 15, p = idx >> 4;
        int b0 = g * 16;
        int un0 = p * 64 + w * 16;
        const u16* encWt = (const u16*)(ws + OFF_ENCWT);
        const u16* xbf = (const u16*)(ws + OFF_X);
        float* ringg = (float*)(ws + RING_OFF + (size_t)g * 524288u);
        int* pz = (int*)(ws + OFF_BAR + g * 64 + 32);

        bf16x8 wfr[4][8];
        float bi[4];
#pragma unroll
        for (int j = 0; j < 4; ++j) {
            int row = j * 256 + un0 + m;
            bi[j] = enc_b[row];
#pragma unroll
            for (int ks = 0; ks < 8; ++ks)
                wfr[j][ks] = *(const bf16x8*)(encWt + row * 256 + ks * 32 + q * 8);
        }
        const u16* xrow = xbf + (size_t)(b0 + m) * (512 * 256) + q * 8;
        bf16x8 xa[8];
#pragma unroll
        for (int s = 0; s < 8; ++s) xa[s] = *(const bf16x8*)(xrow + s * 32);

        for (int t = 0; t < 512; ++t) {
            fx4 a0 = (fx4){bi[0], bi[0], bi[0], bi[0]};
            fx4 a1 = (fx4){bi[1], bi[1], bi[1], bi[1]};
            fx4 a2 = (fx4){bi[2], bi[2], bi[2], bi[2]};
            fx4 a3 = (fx4){bi[3], bi[3], bi[3], bi[3]};
#pragma unroll
            for (int ks = 0; ks < 8; ++ks) {
                a0 = MFMA16(xa[ks], wfr[0][ks], a0);
                a1 = MFMA16(xa[ks], wfr[1][ks], a1);
                a2 = MFMA16(xa[ks], wfr[2][ks], a2);
                a3 = MFMA16(xa[ks], wfr[3][ks], a3);
            }
            // slot layout: [j][u][16 r] fp32; lane (m,q) stores rows q*4..+3
            float* zs = ringg + (t & 7) * 16384 + (un0 + m) * 16 + q * 4;
            asm volatile("global_store_dwordx4 %0, %1, off sc0 sc1" :: "v"(zs), "v"(a0) : "memory");
            asm volatile("global_store_dwordx4 %0, %1, off sc0 sc1" :: "v"(zs + 4096), "v"(a1) : "memory");
            asm volatile("global_store_dwordx4 %0, %1, off sc0 sc1" :: "v"(zs + 8192), "v"(a2) : "memory");
            asm volatile("global_store_dwordx4 %0, %1, off sc0 sc1" :: "v"(zs + 12288), "v"(a3) : "memory");
            if (t < 511) {
                const u16* xA = xrow + (size_t)(t + 1) * 256;   // prefetch next x
#pragma unroll
                for (int s = 0; s < 8; ++s) xa[s] = *(const bf16x8*)(xA + s * 32);
                if (tid == 0 && t >= 7) {
                    // next step overwrites slot (t+1)&7 (holds z[t-7]); all 4
                    // consumer WGs must be past step t-7, i.e. flags(t-6) set:
                    int need = t - 6;
                    const void* fl = ws + OFF_FLG2 + (uint32_t)g * 128u
                                     + (uint32_t)(need & 7) * 16u;
                    for (;;) {
                        u32x4 f = ld_flags4(fl);
                        if ((int)f[0] >= need && (int)f[1] >= need &&
                            (int)f[2] >= need && (int)f[3] >= need) break;
                        if (--budget < 0) break;
                    }
                }
            }
            vmcnt0();                 // z stores (and prefetch) complete
            __syncthreads();
            if (tid == 0)
                __hip_atomic_fetch_add(pz, 1, __ATOMIC_RELAXED, __HIP_MEMORY_SCOPE_AGENT);
        }
        return;
    }

    // ================= consumer =================
    int g = bid & 15, p = bid >> 4;
    int b0 = g * 16;
    int un0 = p * 64 + w * 16;
    const u16* encUt = (const u16*)(ws + OFF_ENCUT);
    const float* ringg = (const float*)(ws + RING_OFF + (size_t)g * 524288u);
    float* csaveg = (float*)(ws + OFF_X + (size_t)g * 4194304u);
    int* pz = (int*)(ws + OFF_BAR + g * 64 + 32);

    bf16x8 ufrag[4][8];
#pragma unroll
    for (int gi = 0; gi < 4; ++gi) {
#pragma unroll
        for (int s = 0; s < 8; ++s)
            ufrag[gi][s] = *(const bf16x8*)(encUt + (gi * 256 + un0 + m) * 256 + s * 32 + q * 8);
    }
    float creg[4] = {0.f, 0.f, 0.f, 0.f};
    int zk = 0;   // cached producer progress (lane 0)

    for (int t = 0; t < 512; ++t) {
        // ---- z[t] certified? (cached; usually skipped — producers run ahead)
        if (lane == 0 && zk <= t) {
            while (--budget > 0) {
                int v = __hip_atomic_load(pz, __ATOMIC_RELAXED, __HIP_MEMORY_SCOPE_AGENT);
                if (v >= 4 * (t + 1)) { zk = v >> 2; break; }
            }
        }
        // ---- peers' h(t) ready? ONE dwordx4 poll of the packed flag line ----
        if (t > 0 && lane == 0) {
            const void* fl = ws + OFF_FLG2 + (uint32_t)g * 128u + (uint32_t)(t & 7) * 16u;
            for (;;) {
                u32x4 f = ld_flags4(fl);
                if ((int)f[0] >= t && (int)f[1] >= t &&
                    (int)f[2] >= t && (int)f[3] >= t) break;
                if (--budget < 0) break;
            }
        }
        asm volatile("" ::: "memory");   // don't hoist loads above the poll

        // ---- h(t) fragments (plain loads: rotating, never-cached lines) ----
        const u16* hA = H + (size_t)t * 65536 + (b0 + m) * 256 + q * 8;
        bf16x8 ha[8];
#pragma unroll
        for (int s = 0; s < 8; ++s) ha[s] = *(const bf16x8*)(hA + s * 32);
        // ---- z[t] (sc loads: ring slots are recycled every 8 steps) ----
        const float* zb = ringg + (t & 7) * 16384 + (un0 + m) * 16 + q * 4;
        fx4 z0, z1, z2, z3;
        asm volatile("global_load_dwordx4 %0, %1, off sc0 sc1" : "=v"(z0) : "v"(zb));
        asm volatile("global_load_dwordx4 %0, %1, off sc0 sc1" : "=v"(z1) : "v"(zb + 4096));
        asm volatile("global_load_dwordx4 %0, %1, off sc0 sc1" : "=v"(z2) : "v"(zb + 8192));
        asm volatile("global_load_dwordx4 %0, %1, off sc0 sc1" : "=v"(z3) : "v"(zb + 12288));

        fx4 acc[4];
#pragma unroll
        for (int gi = 0; gi < 4; ++gi) acc[gi] = (fx4){0.f, 0.f, 0.f, 0.f};
#pragma unroll
        for (int s = 0; s < 8; ++s) {
#pragma unroll
            for (int gi = 0; gi < 4; ++gi)
                acc[gi] = MFMA16(ha[s], ufrag[gi][s], acc[gi]);
        }
        vmcnt0();                                  // z arrived
        __builtin_amdgcn_sched_barrier(0);

        float hreg[4];
#pragma unroll
        for (int r = 0; r < 4; ++r) {
            float pi = acc[0][r] + z0[r];
            float pf = acc[1][r] + z1[r];
            float pg = acc[2][r] + z2[r];
            float po = acc[3][r] + z3[r];
            float cv = sigm(pf) * creg[r] + sigm(pi) * tanh_f(pg);
            creg[r] = cv;
            hreg[r] = sigm(po) * tanh_f(cv);
        }
        // ---- LDS transpose, then coalesced sc-stores of h(t+1) ----
#pragma unroll
        for (int r = 0; r < 4; ++r)
            hbuf[(q * 4 + r) * 64 + w * 16 + m] = f2bf(hreg[r]);
        __syncthreads();
        {
            int row = tid >> 4, c4 = (tid & 15) * 4;
            u32x2 hv = *(const u32x2*)&hbuf[row * 64 + c4];
            const u16* hw = H + (size_t)(t + 1) * 65536 + (b0 + row) * 256 + p * 64 + c4;
            asm volatile("global_store_dwordx2 %0, %1, off sc0 sc1" :: "v"(hw), "v"(hv) : "memory");
        }
        vmcnt0();          // h(t+1) device-visible before the flag
        __syncthreads();   // also guards hbuf reuse next iteration
        if (tid == 0) {
            void* myf = ws + OFF_FLG2 + (uint32_t)g * 128u
                        + (uint32_t)((t + 1) & 7) * 16u + (uint32_t)p * 4u;
            st_flag(myf, (uint32_t)(t + 1));
        }
    }

    // hand off c to the decoder (normal stores; kernel-end flush makes visible)
#pragma unroll
    for (int r = 0; r < 4; ++r)
        csaveg[(q * 4 + r) * 256 + un0 + m] = creg[r];
}

// ---------------------------------------------------------------------------
// Decoder: round-7 structure with the same packed-flag wait (slots continue
// rotating through steps T=512..576; enc left slot values 505..512).
__global__ __launch_bounds__(256, 1) void dec_kernel(const float* __restrict__ cell_b,
                                                     unsigned char* ws) {
    int tid = threadIdx.x;
    int w = tid >> 6, lane = tid & 63, m = lane & 15, q = lane >> 4;
    int bid = blockIdx.x;
    int g = bid & 15, p = bid >> 4;
    int b0 = g * 16;
    int un0 = p * 64 + w * 16;
    int budget = POLL_BUDGET;

    const u16* cellT = (const u16*)(ws + OFF_CELLT);
    u16* H = (u16*)(ws + OFF_H);
    const float* csaveg = (const float*)(ws + OFF_X + (size_t)g * 4194304u);

    bf16x8 wfrag[4][8];
#pragma unroll
    for (int gi = 0; gi < 4; ++gi) {
#pragma unroll
        for (int s = 0; s < 8; ++s)
            wfrag[gi][s] = *(const bf16x8*)(cellT + (gi * 256 + un0 + m) * 256 + s * 32 + q * 8);
    }
    float bi[4], creg[4];
#pragma unroll
    for (int gi = 0; gi < 4; ++gi) bi[gi] = cell_b[gi * 256 + un0 + m];
#pragma unroll
    for (int r = 0; r < 4; ++r) creg[r] = csaveg[(q * 4 + r) * 256 + un0 + m];

    for (int t = 0; t < 64; ++t) {
        int T = 512 + t;   // step index of the h this iteration consumes
        if (t > 0 && lane == 0) {   // t=0: h(512) certified by kernel boundary
            const void* fl = ws + OFF_FLG2 + (uint32_t)g * 128u + (uint32_t)(T & 7) * 16u;
            for (;;) {
                u32x4 f = ld_flags4(fl);
                if ((int)f[0] >= T && (int)f[1] >= T &&
                    (int)f[2] >= T && (int)f[3] >= T) break;
                if (--budget < 0) break;
            }
        }
        asm volatile("" ::: "memory");

        const u16* hA = H + (size_t)T * 65536 + (b0 + m) * 256 + q * 8;
        bf16x8 ha[8];
#pragma unroll
        for (int s = 0; s < 8; ++s) ha[s] = *(const bf16x8*)(hA + s * 32);
        fx4 acc[4];
#pragma unroll
        for (int gi = 0; gi < 4; ++gi) acc[gi] = (fx4){bi[gi], bi[gi], bi[gi], bi[gi]};
#pragma unroll
        for (int s = 0; s < 8; ++s) {
#pragma unroll
            for (int gi = 0; gi < 4; ++gi)
                acc[gi] = MFMA16(ha[s], wfrag[gi][s], acc[gi]);
        }

        const u16* hw = H + (size_t)(T + 1) * 65536 + un0 + m;
#pragma unroll
        for (int r = 0; r < 4; ++r) {
            float cv = sigm(acc[1][r]) * creg[r] + sigm(acc[0][r]) * tanh_f(acc[2][r]);
            creg[r] = cv;
            float hv = sigm(acc[3][r]) * tanh_f(cv);
            uint32_t hb = (uint32_t)f2bf(hv);
            const u16* hp = hw + (b0 + q * 4 + r) * 256;
            asm volatile("global_store_short %0, %1, off sc0 sc1" :: "v"(hp), "v"(hb) : "memory");
        }
        vmcnt0();
        __syncthreads();
        if (tid == 0) {
            void* myf = ws + OFF_FLG2 + (uint32_t)g * 128u
                        + (uint32_t)((T + 1) & 7) * 16u + (uint32_t)p * 4u;
            st_flag(myf, (uint32_t)(T + 1));
        }
    }
}

// ---------------------------------------------------------------------------
// out[(b*seqlen+s)*ncols+col] = H-slot A[s][b][:] @ Bt[col][:] + bias[col]
__global__ __launch_bounds__(256) void out_gemm(const u16* __restrict__ A,
                                                const u16* __restrict__ Bt,
                                                const float* __restrict__ bias,
                                                float* __restrict__ out,
                                                int ncols, int seqlen) {
    int w = threadIdx.x >> 6, lane = threadIdx.x & 63, m = lane & 15, q = lane >> 4;
    int mt = blockIdx.x * 4 + w;
    int s = mt >> 4;
    int b0 = (mt & 15) * 16;
    bf16x8 af[8];
    const u16* Arow = A + ((size_t)s * 256 + b0 + m) * 256 + q * 8;
#pragma unroll
    for (int ss = 0; ss < 8; ++ss) af[ss] = *(const bf16x8*)(Arow + ss * 32);
    int ntiles = ncols >> 4;
    for (int nt = 0; nt < ntiles; ++nt) {
        fx4 acc = (fx4){0.f, 0.f, 0.f, 0.f};
#pragma unroll
        for (int ss = 0; ss < 8; ++ss) {
            bf16x8 bf = *(const bf16x8*)(Bt + (nt * 16 + m) * 256 + ss * 32 + q * 8);
            acc = MFMA16(af[ss], bf, acc);
        }
        int col = nt * 16 + m;
        float bv = bias[col];
#pragma unroll
        for (int r = 0; r < 4; ++r) {
            int b = b0 + q * 4 + r;
            out[((size_t)b * seqlen + s) * ncols + col] = acc[r] + bv;
        }
    }
}

// ---------------------------------------------------------------------------
extern "C" void kernel_launch(void* const* d_in, const int* in_sizes, int n_in,
                              void* d_out, int out_size, void* d_ws, size_t ws_size,
                              hipStream_t stream) {
    const float* inputs = (const float*)d_in[0];
    const float* conv_k = (const float*)d_in[1];
    const float* conv_b = (const float*)d_in[2];
    const float* enc_W  = (const float*)d_in[3];
    const float* enc_U  = (const float*)d_in[4];
    const float* enc_b  = (const float*)d_in[5];
    const float* cell_W = (const float*)d_in[6];
    const float* cell_U = (const float*)d_in[7];
    const float* cell_b = (const float*)d_in[8];
    const float* fore_W = (const float*)d_in[9];
    const float* fore_b = (const float*)d_in[10];
    const float* back_W = (const float*)d_in[11];
    const float* back_b = (const float*)d_in[12];
    unsigned char* ws = (unsigned char*)d_ws;
    float* out = (float*)d_out;

    zero_kernel<<<64, 256, 0, stream>>>(ws);
    prep_kernel<<<1024, 256, 0, stream>>>(enc_W, enc_U, cell_W, cell_U, conv_k, back_W, fore_W, ws);
    conv_kernel<<<2048, 256, 0, stream>>>(inputs, conv_b, ws);
    zero2_kernel<<<1, 256, 0, stream>>>(ws);   // convKt dead; init packed flags
    enc_fused<<<128, 256, 0, stream>>>(enc_b, ws);
    dec_kernel<<<64, 256, 0, stream>>>(cell_b, ws);

    const u16* H = (const u16*)(ws + OFF_H);
    // backcast: slots 1..512 -> out[b][l][64] at float offset 524288
    out_gemm<<<2048, 256, 0, stream>>>(H + (size_t)1 * 65536, (const u16*)(ws + OFF_BWT),
                                       back_b, out + 524288, 64, 512);
    // forecast: slots 513..576 -> out[b][j][32]
    out_gemm<<<256, 256, 0, stream>>>(H + (size_t)513 * 65536, (const u16*)(ws + OFF_FWT),
                                      fore_b, out, 32, 64);
}